// Round 6
// baseline (292.530 us; speedup 1.0000x reference)
//
#include <hip/hip_runtime.h>
#include <cstdint>
#include <cstddef>

#define N_ 2
#define B_ 2
#define D_ 512
#define HW_ 256
#define DK_ 64
#define DKC_ 128
#define G_ 4
#define NBLK_ 32

// ---- workspace offsets (in floats) ----
constexpr size_t OFF_TSR = 0;                       // src_real tokens [(n*hw), b, d]  (reused as T3r partial kc=1)
constexpr size_t OFF_TSI = 524288;                  // (reused as T3i partial kc=1)
constexpr size_t OFF_TTR = 1048576;
constexpr size_t OFF_TTI = 1572864;
constexpr size_t OFF_QSR = 2097152;                 // rel q (src) [(n*hw), b, 64]
constexpr size_t OFF_QSI = OFF_QSR + 65536;
constexpr size_t OFF_QTR = OFF_QSI + 65536;
constexpr size_t OFF_QTI = OFF_QTR + 65536;
constexpr size_t OFF_AS  = OFF_QTI + 65536;         // self-attn A (src) [nb,256,256]
constexpr size_t OFF_AT  = OFF_AS + 262144;
constexpr size_t OFF_YSR = OFF_AT + 262144;         // src + attn out (then mem after scale)
constexpr size_t OFF_YSI = OFF_YSR + 524288;
constexpr size_t OFF_YTR = OFF_YSI + 524288;        // tgt + attn out (then x after scale)
constexpr size_t OFF_YTI = OFF_YTR + 524288;
constexpr size_t OFF_QCR = OFF_YTI + 524288;        // cross q [l,b,128]
constexpr size_t OFF_QCI = OFF_QCR + 131072;
constexpr size_t OFF_KCR = OFF_QCI + 131072;
constexpr size_t OFF_KCI = OFF_KCR + 131072;
constexpr size_t OFF_AC  = OFF_KCI + 131072;        // cross scores -> A [b,512,512]
constexpr size_t OFF_T3R = OFF_AC + 524288;         // t3 partial kc=0 (then z after combine)
constexpr size_t OFF_T3I = OFF_T3R + 524288;
constexpr size_t OFF_MR  = OFF_T3I + 524288;        // mask scalar [b,512]
constexpr size_t OFF_MI  = OFF_MR + 1024;
constexpr size_t OFF_P1  = OFF_MI + 1024;           // partials (16 qty-groups x 32)
constexpr size_t OFF_P2  = OFF_P1 + 512;
constexpr size_t OFF_P3  = OFF_P2 + 512;
constexpr size_t OFF_S1  = OFF_P3 + 256;            // scales
constexpr size_t OFF_S2  = OFF_S1 + 16;
constexpr size_t OFF_SZ  = OFF_S2 + 16;

// ---- reductions ----
template<int NT>
__device__ __forceinline__ float blk_sum(float v, float* sh) {
  int tid = threadIdx.x;
  sh[tid] = v; __syncthreads();
  #pragma unroll
  for (int s = NT/2; s > 0; s >>= 1) { if (tid < s) sh[tid] += sh[tid+s]; __syncthreads(); }
  float r = sh[0]; __syncthreads(); return r;
}
template<int NT>
__device__ __forceinline__ float blk_max(float v, float* sh) {
  int tid = threadIdx.x;
  sh[tid] = v; __syncthreads();
  #pragma unroll
  for (int s = NT/2; s > 0; s >>= 1) { if (tid < s) sh[tid] = fmaxf(sh[tid], sh[tid+s]); __syncthreads(); }
  float r = sh[0]; __syncthreads(); return r;
}
__device__ __forceinline__ float wave_sum32(float v) {   // full 64-lane sum (xor tree)
  #pragma unroll
  for (int o = 16; o; o >>= 1) v += __shfl_xor(v, o, 64);
  return v;
}
__device__ __forceinline__ float wave_sum64(float v) {
  #pragma unroll
  for (int o = 32; o; o >>= 1) v += __shfl_xor(v, o, 64);
  return v;
}
__device__ __forceinline__ float wave_max64(float v) {
  #pragma unroll
  for (int o = 32; o; o >>= 1) v = fmaxf(v, __shfl_xor(v, o, 64));
  return v;
}

// ---- 1: tokenize transpose: [n,b,d,hw] -> [(n*hw),b,d] ----
__global__ void k_transpose(const float* sR, const float* sI, const float* tR, const float* tI, float* ws) {
  int which = blockIdx.y;
  const float* in = (which==0)? sR : (which==1)? sI : (which==2)? tR : tI;
  float* out = ws + ((which==0)? OFF_TSR : (which==1)? OFF_TSI : (which==2)? OFF_TTR : OFF_TTI);
  int bx = blockIdx.x;               // 128 = nb(4)*dt(8)*pt(4)
  int pt = bx & 3, dt = (bx>>2)&7, nb = bx>>5;
  int ni = nb>>1, bi = nb&1;
  __shared__ float tile[64][65];
  int tid = threadIdx.x;
  int p0 = pt*64, d0 = dt*64;
  #pragma unroll
  for (int it=0; it<16; ++it) {
    int i = it*256 + tid; int row = i>>6, col = i&63;   // row=d_local, col=p_local
    tile[row][col] = in[(size_t)(nb*D_ + d0+row)*HW_ + p0+col];
  }
  __syncthreads();
  #pragma unroll
  for (int it=0; it<16; ++it) {
    int i = it*256 + tid; int row = i>>6, col = i&63;   // row=p_local, col=d_local
    out[(size_t)((ni*HW_ + p0+row)*B_ + bi)*D_ + d0+col] = tile[col][row];
  }
}

// ---- 2: rel q projection + cnorm (8 rows/block, W amortized) ----
__global__ void __launch_bounds__(256) k_qrel(float* ws, const float* WK) {
  int bx = blockIdx.x;               // 256 = which(2)*rg(128)
  int rg = bx & 127, which = bx >> 7;
  const float* Tr = ws + (which ? OFF_TTR : OFF_TSR);
  const float* Ti = ws + (which ? OFF_TTI : OFF_TSI);
  float* Qr = ws + (which ? OFF_QTR : OFF_QSR);
  float* Qi = ws + (which ? OFF_QTI : OFF_QSI);
  int R0 = rg*8;
  __shared__ float Xr[8][512], Xi[8][512];
  int tid = threadIdx.x;
  const float4* tr4 = (const float4*)(Tr + (size_t)R0*D_);
  const float4* ti4 = (const float4*)(Ti + (size_t)R0*D_);
  #pragma unroll
  for (int it=0; it<4; ++it) {
    int i = it*256 + tid;
    ((float4*)&Xr[0][0])[i] = tr4[i];
    ((float4*)&Xi[0][0])[i] = ti4[i];
  }
  __syncthreads();
  int row = tid >> 5, col2 = (tid & 31)*2;
  float a0r=0.f, a0i=0.f, a1r=0.f, a1i=0.f;
  #pragma unroll 4
  for (int d=0; d<512; ++d) {
    float2 w = *(const float2*)&WK[(size_t)d*DK_ + col2];
    float xr = Xr[row][d], xi = Xi[row][d];
    a0r += xr*w.x; a1r += xr*w.y;
    a0i += xi*w.x; a1i += xi*w.y;
  }
  float ss = wave_sum32(a0r*a0r + a1r*a1r + a0i*a0i + a1i*a1i);
  float inv = 1.f / sqrtf(ss + 1e-12f);
  size_t o = (size_t)(R0+row)*DK_ + col2;
  Qr[o]   = a0r*inv; Qr[o+1] = a1r*inv;
  Qi[o]   = a0i*inv; Qi[o+1] = a1i*inv;
}

// ---- 2b: gram scores G = Qr Qr^T + Qi Qi^T, written into A buffers ----
__global__ void __launch_bounds__(128) k_gram(float* ws) {
  int bx = blockIdx.x;               // 256 = which(2)*nb(4)*qt(8)*lt(4)
  int lt = bx & 3, qt = (bx>>2)&7, nb = (bx>>5)&3, which = bx>>7;
  int ni = nb>>1, bi = nb&1;
  const float* Qr = ws + (which ? OFF_QTR : OFF_QSR);
  const float* Qi = ws + (which ? OFF_QTI : OFF_QSI);
  float* A = ws + (which ? OFF_AT : OFF_AS) + (size_t)nb*65536;
  __shared__ float Qrs[32][33], Qis[32][33], Krs[32][68], Kis[32][68];
  int tid = threadIdx.x, ty = tid>>4, tx = tid&15;
  int ty4 = ty*4, tx4 = tx*4;
  float acc[4][4] = {};
  for (int c = 0; c < 2; ++c) {
    #pragma unroll
    for (int it = 0; it < 8; ++it) {
      int i = it*128 + tid; int row = i>>5, col = i&31;
      size_t qa = (size_t)((ni*HW_ + qt*32+row)*B_ + bi)*DK_ + c*32 + col;
      Qrs[row][col] = Qr[qa];
      Qis[row][col] = Qi[qa];
    }
    #pragma unroll
    for (int it = 0; it < 16; ++it) {
      int i = it*128 + tid; int kk = i&31, col = i>>5;
      size_t ka = (size_t)((ni*HW_ + lt*64+col)*B_ + bi)*DK_ + c*32 + kk;
      Krs[kk][col] = Qr[ka];
      Kis[kk][col] = Qi[ka];
    }
    __syncthreads();
    #pragma unroll
    for (int kk = 0; kk < 32; ++kk) {
      float4 kr = *(const float4*)&Krs[kk][tx4];
      float4 ki = *(const float4*)&Kis[kk][tx4];
      #pragma unroll
      for (int i = 0; i < 4; ++i) {
        float qr = Qrs[ty4+i][kk], qi = Qis[ty4+i][kk];
        acc[i][0] += qr*kr.x + qi*ki.x;
        acc[i][1] += qr*kr.y + qi*ki.y;
        acc[i][2] += qr*kr.z + qi*ki.z;
        acc[i][3] += qr*kr.w + qi*ki.w;
      }
    }
    __syncthreads();
  }
  #pragma unroll
  for (int i = 0; i < 4; ++i)
    #pragma unroll
    for (int j = 0; j < 4; ++j)
      A[(size_t)(qt*32+ty4+i)*256 + lt*64+tx4+j] = acc[i][j];
}

// ---- 3: rel self-attn emb scores + softmax (gram pre-seeded in A) ----
// Wave-per-q-row, zero barriers/LDS. Register double-buffer (8-k chunks),
// sched_barrier(0) pins the loads ABOVE the previous chunk's FMAs so the
// compiler cannot collapse the pipeline (round-5 failure: VGPR=44).
#define LOADCH(BR, BI, C)                                        \
  _Pragma("unroll")                                              \
  for (int t = 0; t < 8; ++t) {                                  \
    BR[t] = er4[(size_t)((C)*8 + t) * 16384];                    \
    BI[t] = ei4[(size_t)((C)*8 + t) * 16384];                    \
  }                                                              \
  __builtin_amdgcn_sched_barrier(0);
#define CONSUME(BR, BI, K0)                                      \
  _Pragma("unroll")                                              \
  for (int t = 0; t < 8; ++t) {                                  \
    float fr = __shfl(qvr, (K0) + t);                            \
    float fi = __shfl(qvi, (K0) + t);                            \
    a0 += fr*BR[t].x + fi*BI[t].x;                               \
    a1 += fr*BR[t].y + fi*BI[t].y;                               \
    a2 += fr*BR[t].z + fi*BI[t].z;                               \
    a3 += fr*BR[t].w + fi*BI[t].w;                               \
  }                                                              \
  __builtin_amdgcn_sched_barrier(0);

__global__ void __launch_bounds__(256, 2) k_selfattn(float* ws, const float* esr, const float* esi,
                                                     const float* etr, const float* eti) {
  int idx = blockIdx.x;              // 512 = which(2)*nb(4)*qg(64)
  int qg = idx & 63, nb = (idx>>6)&3, which = idx>>8;
  int ni = nb>>1, bi = nb&1;
  const float* Qr = ws + (which ? OFF_QTR : OFF_QSR);
  const float* Qi = ws + (which ? OFF_QTI : OFF_QSI);
  const float* er = which ? etr : esr;
  const float* ei = which ? eti : esi;
  int tid = threadIdx.x, w = tid>>6, lane = tid&63;
  int iq = qg*4 + w;                 // each wave owns one q-row; no inter-wave sync
  float* Arow = ws + (which ? OFF_AT : OFF_AS) + (size_t)nb*65536 + (size_t)iq*256;
  int tokq = ni*HW_ + iq;
  float qvr = Qr[(size_t)(tokq*B_ + bi)*DK_ + lane];   // lane = k index
  float qvi = Qi[(size_t)(tokq*B_ + bi)*DK_ + lane];
  int l0 = lane*4;
  size_t eb = (size_t)nb*4194304 + (size_t)iq*256 + l0;
  const float4* er4 = (const float4*)&er[eb];
  const float4* ei4 = (const float4*)&ei[eb];
  float4 Ra[8], Ia[8], Rb[8], Ib[8];
  float a0=0.f, a1=0.f, a2=0.f, a3=0.f;
  LOADCH(Ra, Ia, 0)
  LOADCH(Rb, Ib, 1)
  CONSUME(Ra, Ia, 0)
  LOADCH(Ra, Ia, 2)
  CONSUME(Rb, Ib, 8)
  LOADCH(Rb, Ib, 3)
  CONSUME(Ra, Ia, 16)
  LOADCH(Ra, Ia, 4)
  CONSUME(Rb, Ib, 24)
  LOADCH(Rb, Ib, 5)
  CONSUME(Ra, Ia, 32)
  LOADCH(Ra, Ia, 6)
  CONSUME(Rb, Ib, 40)
  LOADCH(Rb, Ib, 7)
  CONSUME(Ra, Ia, 48)
  CONSUME(Rb, Ib, 56)
  float4 g = *(const float4*)&Arow[l0];    // gram seed from k_gram
  float s0 = (a0 + g.x)*30.f, s1 = (a1 + g.y)*30.f;
  float s2 = (a2 + g.z)*30.f, s3 = (a3 + g.w)*30.f;
  float m = wave_max64(fmaxf(fmaxf(s0,s1), fmaxf(s2,s3)));
  float e0 = __expf(s0-m), e1 = __expf(s1-m), e2 = __expf(s2-m), e3 = __expf(s3-m);
  float inv = 1.f / wave_sum64(e0+e1+e2+e3);
  *(float4*)&Arow[l0] = make_float4(e0*inv, e1*inv, e2*inv, e3*inv);
}

// ---- 4: Y = tok + A @ tok  (32x64 tiles, 128 thr, r & i together) ----
__global__ void __launch_bounds__(128) k_selfapply(float* ws) {
  int bx = blockIdx.x;               // 512 = which(2)*nb(4)*qt(8)*dt(8)
  int dt = bx & 7, qt = (bx>>3)&7, nb = (bx>>6)&3, which = bx>>8;
  int ni = nb>>1, bi = nb&1;
  const float* A  = ws + (which ? OFF_AT : OFF_AS) + (size_t)nb*65536;
  const float* Xr = ws + (which ? OFF_TTR : OFF_TSR);
  const float* Xi = ws + (which ? OFF_TTI : OFF_TSI);
  float* Yr = ws + (which ? OFF_YTR : OFF_YSR);
  float* Yi = ws + (which ? OFF_YTI : OFF_YSI);
  __shared__ float As[32][33], Xrs[32][68], Xis[32][68];
  int tid = threadIdx.x, ty = tid>>4, tx = tid&15;
  int ty4 = ty*4, tx4 = tx*4;
  float ar[4][4] = {}, ai[4][4] = {};
  for (int c = 0; c < 8; ++c) {
    #pragma unroll
    for (int it = 0; it < 8; ++it) {
      int i = it*128 + tid; int row = i>>5, col = i&31;
      As[row][col] = A[(size_t)(qt*32+row)*256 + c*32+col];
    }
    #pragma unroll
    for (int it = 0; it < 16; ++it) {
      int i = it*128 + tid; int row = i>>6, col = i&63;
      size_t xb = (size_t)((ni*HW_ + c*32+row)*B_ + bi)*D_ + dt*64+col;
      Xrs[row][col] = Xr[xb]; Xis[row][col] = Xi[xb];
    }
    __syncthreads();
    #pragma unroll
    for (int kk = 0; kk < 32; ++kk) {
      float4 vr = *(const float4*)&Xrs[kk][tx4];
      float4 vi = *(const float4*)&Xis[kk][tx4];
      #pragma unroll
      for (int i = 0; i < 4; ++i) {
        float a = As[ty4+i][kk];
        ar[i][0] += a*vr.x; ar[i][1] += a*vr.y; ar[i][2] += a*vr.z; ar[i][3] += a*vr.w;
        ai[i][0] += a*vi.x; ai[i][1] += a*vi.y; ai[i][2] += a*vi.z; ai[i][3] += a*vi.w;
      }
    }
    __syncthreads();
  }
  #pragma unroll
  for (int i = 0; i < 4; ++i) {
    size_t o = (size_t)((ni*HW_ + qt*32 + ty4+i)*B_ + bi)*D_ + dt*64 + tx4;
    #pragma unroll
    for (int j = 0; j < 4; ++j) { Yr[o+j] = Xr[o+j] + ar[i][j]; Yi[o+j] = Xi[o+j] + ai[i][j]; }
  }
}

// ---- 5: ss = sum(Y^2) per (n,b) for the 4 Y arrays ----
__global__ void k_reduce4(float* ws) {
  int qy = blockIdx.y;
  const float* a = ws + ((qy==0)? OFF_YSR : (qy==1)? OFF_YSI : (qy==2)? OFF_YTR : OFF_YTI);
  int g = blockIdx.x / NBLK_, blk = blockIdx.x % NBLK_;
  int ni = g>>1, bi = g&1;
  int tid = threadIdx.x;
  float acc = 0.f;
  for (int p = blk; p < HW_; p += NBLK_) {
    const float* row = a + (size_t)((ni*HW_ + p)*B_ + bi)*D_;
    for (int d = tid; d < D_; d += 256) { float v = row[d]; acc += v*v; }
  }
  __shared__ float sh[256];
  float s = blk_sum<256>(acc, sh);
  if (!tid) ws[OFF_P1 + (size_t)(qy*G_ + g)*NBLK_ + blk] = s;
}

// ---- finalize: scale = 4*rsqrt(ss + 1e-5) ----
__global__ void k_finalize(const float* part, float* scales, int nq) {
  int t = threadIdx.x;
  if (t < nq) {
    float ss = 0.f;
    for (int j = 0; j < NBLK_; ++j) ss += part[t*NBLK_ + j];
    scales[t] = 4.f * rsqrtf(ss + 1e-5f);
  }
}

// ---- 7: Y *= scale  (mem / x) ----
__global__ void k_applyscale(float* ws, const float* scales) {
  int qy = blockIdx.y;
  float* a = ws + ((qy==0)? OFF_YSR : (qy==1)? OFF_YSI : (qy==2)? OFF_YTR : OFF_YTI);
  int idx4 = blockIdx.x*256 + threadIdx.x;
  int elem = idx4*4;
  int bi = (elem / D_) & 1;
  int r = elem >> 10;
  int ni = r >> 8;
  float s = scales[qy*G_ + ni*2 + bi];
  float4 v = ((float4*)a)[idx4];
  v.x *= s; v.y *= s; v.z *= s; v.w *= s;
  ((float4*)a)[idx4] = v;
}

// ---- 8: cross q/k projection + cnorm (8 rows/block, W amortized) ----
__global__ void __launch_bounds__(256) k_crossproj(float* ws, const float* W) {
  int bx = blockIdx.x;               // 256 = isK(2)*rg(128)
  int rg = bx & 127, isK = bx >> 7;
  const float* inR = ws + (isK ? OFF_YSR : OFF_YTR);
  const float* inI = ws + (isK ? OFF_YSI : OFF_YTI);
  float* oR = ws + (isK ? OFF_KCR : OFF_QCR);
  float* oI = ws + (isK ? OFF_KCI : OFF_QCI);
  int R0 = rg*8;
  __shared__ float Xr[8][512], Xi[8][512];
  int tid = threadIdx.x;
  const float4* xr4 = (const float4*)(inR + (size_t)R0*D_);
  const float4* xi4 = (const float4*)(inI + (size_t)R0*D_);
  #pragma unroll
  for (int it=0; it<4; ++it) {
    int i = it*256 + tid;
    ((float4*)&Xr[0][0])[i] = xr4[i];
    ((float4*)&Xi[0][0])[i] = xi4[i];
  }
  __syncthreads();
  // row = tid>>5 (0..7); its 128 cols are covered by 32 lanes x 4 cols,
  // so the 32-lane reduce yields the COMPLETE row sum.
  int row = tid >> 5, col4 = (tid & 31)*4;
  float ar[4]={}, ai[4]={};
  #pragma unroll 4
  for (int d=0; d<512; ++d) {
    float4 w = *(const float4*)&W[(size_t)d*DKC_ + col4];
    float xr = Xr[row][d], xi = Xi[row][d];
    ar[0] += xr*w.x; ar[1] += xr*w.y; ar[2] += xr*w.z; ar[3] += xr*w.w;
    ai[0] += xi*w.x; ai[1] += xi*w.y; ai[2] += xi*w.z; ai[3] += xi*w.w;
  }
  float ps = ar[0]*ar[0]+ar[1]*ar[1]+ar[2]*ar[2]+ar[3]*ar[3]
           + ai[0]*ai[0]+ai[1]*ai[1]+ai[2]*ai[2]+ai[3]*ai[3];
  float ss = wave_sum32(ps);
  float inv = 1.f / sqrtf(ss + 1e-12f);
  size_t o = (size_t)(R0+row)*DKC_ + col4;
  oR[o]   = ar[0]*inv; oR[o+1] = ar[1]*inv; oR[o+2] = ar[2]*inv; oR[o+3] = ar[3]*inv;
  oI[o]   = ai[0]*inv; oI[o+1] = ai[1]*inv; oI[o+2] = ai[2]*inv; oI[o+3] = ai[3]*inv;
}

// ---- 9: raw cross scores S = Qr Kr^T + Qi Ki^T  (32x64 tiles) ----
__global__ void __launch_bounds__(128) k_crossscore(float* ws) {
  int bx = blockIdx.x;               // 256 = bi(2)*qt(16)*lt(8)
  int lt = bx & 7, qt = (bx>>3)&15, bi = bx>>7;
  const float* Qr = ws + OFF_QCR; const float* Qi = ws + OFF_QCI;
  const float* Kr = ws + OFF_KCR; const float* Ki = ws + OFF_KCI;
  float* S = ws + OFF_AC + (size_t)bi*262144;
  __shared__ float Qrs[32][33], Qis[32][33], Krs[32][68], Kis[32][68];
  int tid = threadIdx.x, ty = tid>>4, tx = tid&15;
  int ty4 = ty*4, tx4 = tx*4;
  float acc[4][4] = {};
  for (int c = 0; c < 4; ++c) {
    #pragma unroll
    for (int it = 0; it < 8; ++it) {
      int i = it*128 + tid; int row = i>>5, col = i&31;
      Qrs[row][col] = Qr[(size_t)((qt*32+row)*B_ + bi)*DKC_ + c*32 + col];
      Qis[row][col] = Qi[(size_t)((qt*32+row)*B_ + bi)*DKC_ + c*32 + col];
    }
    #pragma unroll
    for (int it = 0; it < 16; ++it) {
      int i = it*128 + tid; int kk = i&31, col = i>>5;
      Krs[kk][col] = Kr[(size_t)((lt*64+col)*B_ + bi)*DKC_ + c*32 + kk];
      Kis[kk][col] = Ki[(size_t)((lt*64+col)*B_ + bi)*DKC_ + c*32 + kk];
    }
    __syncthreads();
    #pragma unroll
    for (int kk = 0; kk < 32; ++kk) {
      float4 kr = *(const float4*)&Krs[kk][tx4];
      float4 ki = *(const float4*)&Kis[kk][tx4];
      #pragma unroll
      for (int i = 0; i < 4; ++i) {
        float qr = Qrs[ty4+i][kk], qi = Qis[ty4+i][kk];
        acc[i][0] += qr*kr.x + qi*ki.x;
        acc[i][1] += qr*kr.y + qi*ki.y;
        acc[i][2] += qr*kr.z + qi*ki.z;
        acc[i][3] += qr*kr.w + qi*ki.w;
      }
    }
    __syncthreads();
  }
  #pragma unroll
  for (int i = 0; i < 4; ++i)
    #pragma unroll
    for (int j = 0; j < 4; ++j)
      S[(size_t)(qt*32+ty4+i)*512 + lt*64+tx4+j] = acc[i][j];
}

// ---- 10: softmax per row (in-place) + mask scalars m = A @ pos ----
__global__ void k_softmaxrow(float* ws, const float* posr, const float* posi) {
  int bx = blockIdx.x;               // 1024 = b*512
  int bi = bx >> 9, iq = bx & 511;
  float* row = ws + OFF_AC + (size_t)bi*262144 + (size_t)iq*512;
  int tid = threadIdx.x;             // 256
  float s0 = row[tid]*30.f, s1 = row[tid+256]*30.f;
  __shared__ float sh[256];
  float m = blk_max<256>(fmaxf(s0, s1), sh);
  float e0 = __expf(s0 - m), e1 = __expf(s1 - m);
  float sum = blk_sum<256>(e0 + e1, sh);
  float inv = 1.f / sum;
  float a0 = e0*inv, a1 = e1*inv;
  row[tid] = a0; row[tid+256] = a1;
  float pr0 = posr[bi*HW_ + tid],        pr1 = posr[(B_+bi)*HW_ + tid];
  float pi0 = posi[bi*HW_ + tid],        pi1 = posi[(B_+bi)*HW_ + tid];
  float mr = blk_sum<256>(a0*pr0 + a1*pr1, sh);
  float mi = blk_sum<256>(a0*pi0 + a1*pi1, sh);
  if (!tid) { ws[OFF_MR + bi*512 + iq] = mr; ws[OFF_MI + bi*512 + iq] = mi; }
}

// ---- 11: t3 = A @ (mem * pos), split-K=2, partials ----
__global__ void __launch_bounds__(128) k_crossapply(float* ws, const float* posr, const float* posi) {
  int bx = blockIdx.x;               // 512 = kc(2)*bi(2)*qt(16)*dt(8)
  int dt = bx & 7, qt = (bx>>3)&15, bi = (bx>>7)&1, kc = bx>>8;
  const float* A  = ws + OFF_AC + (size_t)bi*262144;
  const float* Mr = ws + OFF_YSR; const float* Mi = ws + OFF_YSI;
  float* Pr = ws + (kc ? OFF_TSR : OFF_T3R);
  float* Pi = ws + (kc ? OFF_TSI : OFF_T3I);
  __shared__ float As[32][33], Vrs[32][68], Vis[32][68];
  int tid = threadIdx.x, ty = tid>>4, tx = tid&15;
  int ty4 = ty*4, tx4 = tx*4;
  float ar[4][4] = {}, ai[4][4] = {};
  for (int c = 0; c < 8; ++c) {
    int kb = kc*256 + c*32;
    #pragma unroll
    for (int it = 0; it < 8; ++it) {
      int i = it*128 + tid; int row = i>>5, col = i&31;
      As[row][col] = A[(size_t)(qt*32+row)*512 + kb+col];
    }
    #pragma unroll
    for (int it = 0; it < 16; ++it) {
      int i = it*128 + tid; int row = i>>6, col = i&63;
      int l = kb + row; int nil = l>>8, pl = l&255;
      float pvr = posr[(nil*B_ + bi)*HW_ + pl];
      float pvi = posi[(nil*B_ + bi)*HW_ + pl];
      size_t vb = (size_t)(l*B_ + bi)*D_ + dt*64+col;
      Vrs[row][col] = Mr[vb] * pvr;
      Vis[row][col] = Mi[vb] * pvi;
    }
    __syncthreads();
    #pragma unroll
    for (int kk = 0; kk < 32; ++kk) {
      float4 vr = *(const float4*)&Vrs[kk][tx4];
      float4 vi = *(const float4*)&Vis[kk][tx4];
      #pragma unroll
      for (int i = 0; i < 4; ++i) {
        float a = As[ty4+i][kk];
        ar[i][0] += a*vr.x; ar[i][1] += a*vr.y; ar[i][2] += a*vr.z; ar[i][3] += a*vr.w;
        ai[i][0] += a*vi.x; ai[i][1] += a*vi.y; ai[i][2] += a*vi.z; ai[i][3] += a*vi.w;
      }
    }
    __syncthreads();
  }
  #pragma unroll
  for (int i = 0; i < 4; ++i) {
    size_t o = (size_t)((qt*32+ty4+i)*B_ + bi)*D_ + dt*64 + tx4;
    #pragma unroll
    for (int j = 0; j < 4; ++j) { Pr[o+j] = ar[i][j]; Pi[o+j] = ai[i][j]; }
  }
}

// ---- 12: ss for (x*m)^2 (r,i) and (x+t3)^2 (r,i); t3 = sum of 2 partials ----
__global__ void k_reducey24(float* ws) {
  int qy = blockIdx.y;
  int g = blockIdx.x / NBLK_, blk = blockIdx.x % NBLK_;
  int ni = g>>1, bi = g&1;
  const float* X   = ws + ((qy==0 || qy==2) ? OFF_YTR : OFF_YTI);
  const float* T3a = ws + ((qy==2) ? OFF_T3R : OFF_T3I);
  const float* T3b = ws + ((qy==2) ? OFF_TSR : OFF_TSI);
  const float* M   = ws + ((qy==0) ? OFF_MR : OFF_MI);
  int tid = threadIdx.x;
  float acc = 0.f;
  for (int p = blk; p < HW_; p += NBLK_) {
    int l = ni*HW_ + p;
    size_t rb = (size_t)(l*B_ + bi)*D_;
    if (qy < 2) {
      float m = M[bi*512 + l];
      for (int d = tid; d < D_; d += 256) { float v = X[rb+d]*m; acc += v*v; }
    } else {
      for (int d = tid; d < D_; d += 256) { float v = X[rb+d] + T3a[rb+d] + T3b[rb+d]; acc += v*v; }
    }
  }
  __shared__ float sh[256];
  float s = blk_sum<256>(acc, sh);
  if (!tid) ws[OFF_P2 + (size_t)(qy*G_ + g)*NBLK_ + blk] = s;
}

// ---- 14: z = a2*(x*m) + a4*(x+t3) (into T3a) + ss(z) partials ----
__global__ void k_combine(float* ws, const float* scales2) {
  int y = blockIdx.y;                // 0=r, 1=i
  int g = blockIdx.x / NBLK_, blk = blockIdx.x % NBLK_;
  int ni = g>>1, bi = g&1;
  const float* X   = ws + (y ? OFF_YTI : OFF_YTR);
  float* T3a       = ws + (y ? OFF_T3I : OFF_T3R);
  const float* T3b = ws + (y ? OFF_TSI : OFF_TSR);
  const float* M   = ws + (y ? OFF_MI : OFF_MR);
  float a2 = scales2[y*G_ + g], a4 = scales2[(2+y)*G_ + g];
  int tid = threadIdx.x;
  float acc = 0.f;
  for (int p = blk; p < HW_; p += NBLK_) {
    int l = ni*HW_ + p;
    float m = M[bi*512 + l];
    size_t rb = (size_t)(l*B_ + bi)*D_;
    for (int d = tid; d < D_; d += 256) {
      float x = X[rb+d];
      float z = a2*(x*m) + a4*(x + T3a[rb+d] + T3b[rb+d]);
      T3a[rb+d] = z;
      acc += z*z;
    }
  }
  __shared__ float sh[256];
  float s = blk_sum<256>(acc, sh);
  if (!tid) ws[OFF_P3 + (size_t)(y*G_ + g)*NBLK_ + blk] = s;
}

// ---- 16: out = z*scale; feat = transpose(out) ----
__global__ void k_final(float* ws, const float* scalesZ, float* out) {
  int y = blockIdx.y;                // 0=r, 1=i
  int bx = blockIdx.x;               // 128 = nb(4)*dt(8)*pt(4)
  int pt = bx & 3, dt = (bx>>2)&7, nb = bx>>5;
  int ni = nb>>1, bi = nb&1;
  const float* Z = ws + (y ? OFF_T3I : OFF_T3R);
  float s = scalesZ[y*G_ + nb];
  float* o1 = out + (size_t)y*524288;        // out_r / out_i
  float* o2 = out + (size_t)(2+y)*524288;    // feat_r / feat_i
  __shared__ float tile[64][65];
  int tid = threadIdx.x;
  int p0 = pt*64, d0 = dt*64;
  #pragma unroll
  for (int it = 0; it < 16; ++it) {
    int i = it*256 + tid; int row = i>>6, col = i&63;   // row=p_local, col=d_local
    size_t idx = (size_t)((ni*HW_ + p0+row)*B_ + bi)*D_ + d0+col;
    float v = Z[idx] * s;
    o1[idx] = v;
    tile[row][col] = v;
  }
  __syncthreads();
  #pragma unroll
  for (int it = 0; it < 16; ++it) {
    int i = it*256 + tid; int row = i>>6, col = i&63;   // row=d_local, col=p_local
    o2[(size_t)(nb*D_ + d0+row)*HW_ + p0+col] = tile[col][row];
  }
}

extern "C" void kernel_launch(void* const* d_in, const int* in_sizes, int n_in,
                              void* d_out, int out_size, void* d_ws, size_t ws_size,
                              hipStream_t stream) {
  const float* srcR = (const float*)d_in[0];
  const float* srcI = (const float*)d_in[1];
  const float* tgtR = (const float*)d_in[2];
  const float* tgtI = (const float*)d_in[3];
  const float* esr  = (const float*)d_in[4];
  const float* esi  = (const float*)d_in[5];
  const float* etr  = (const float*)d_in[6];
  const float* eti  = (const float*)d_in[7];
  const float* posR = (const float*)d_in[8];
  const float* posI = (const float*)d_in[9];
  const float* WKrel   = (const float*)d_in[10];
  const float* WKcross = (const float*)d_in[11];
  float* ws  = (float*)d_ws;
  float* out = (float*)d_out;

  k_transpose <<<dim3(128,4), 256, 0, stream>>>(srcR, srcI, tgtR, tgtI, ws);
  k_qrel      <<<256, 256, 0, stream>>>(ws, WKrel);
  k_gram      <<<256, 128, 0, stream>>>(ws);
  k_selfattn  <<<512, 256, 0, stream>>>(ws, esr, esi, etr, eti);
  k_selfapply <<<512, 128, 0, stream>>>(ws);
  k_reduce4   <<<dim3(G_*NBLK_,4), 256, 0, stream>>>(ws);
  k_finalize  <<<1, 64, 0, stream>>>(ws + OFF_P1, ws + OFF_S1, 16);
  k_applyscale<<<dim3(512,4), 256, 0, stream>>>(ws, ws + OFF_S1);
  k_crossproj <<<256, 256, 0, stream>>>(ws, WKcross);
  k_crossscore<<<256, 128, 0, stream>>>(ws);
  k_softmaxrow<<<1024, 256, 0, stream>>>(ws, posR, posI);
  k_crossapply<<<512, 128, 0, stream>>>(ws, posR, posI);
  k_reducey24 <<<dim3(G_*NBLK_,4), 256, 0, stream>>>(ws);
  k_finalize  <<<1, 64, 0, stream>>>(ws + OFF_P2, ws + OFF_S2, 16);
  k_combine   <<<dim3(G_*NBLK_,2), 256, 0, stream>>>(ws, ws + OFF_S2);
  k_finalize  <<<1, 64, 0, stream>>>(ws + OFF_P3, ws + OFF_SZ, 8);
  k_final     <<<dim3(128,2), 256, 0, stream>>>(ws, ws + OFF_SZ, out);
}

// Round 7
// 283.875 us; speedup vs baseline: 1.0305x; 1.0305x over previous
//
#include <hip/hip_runtime.h>
#include <cstdint>
#include <cstddef>

#define N_ 2
#define B_ 2
#define D_ 512
#define HW_ 256
#define DK_ 64
#define DKC_ 128
#define G_ 4
#define NBLK_ 32

// ---- workspace offsets (in floats) ----
constexpr size_t OFF_TSR = 0;                       // src tokens (reused as T3 partial kc=1)
constexpr size_t OFF_TSI = 524288;
constexpr size_t OFF_TTR = 1048576;
constexpr size_t OFF_TTI = 1572864;
constexpr size_t OFF_QSR = 2097152;                 // rel q (src) [(n*hw), b, 64]
constexpr size_t OFF_QSI = OFF_QSR + 65536;
constexpr size_t OFF_QTR = OFF_QSI + 65536;
constexpr size_t OFF_QTI = OFF_QTR + 65536;
constexpr size_t OFF_AS  = OFF_QTI + 65536;         // self-attn A (src) [nb,256,256]
constexpr size_t OFF_AT  = OFF_AS + 262144;
constexpr size_t OFF_YSR = OFF_AT + 262144;         // src + attn out (UNSCALED mem)
constexpr size_t OFF_YSI = OFF_YSR + 524288;
constexpr size_t OFF_YTR = OFF_YSI + 524288;        // tgt + attn out (UNSCALED x)
constexpr size_t OFF_YTI = OFF_YTR + 524288;
constexpr size_t OFF_QCR = OFF_YTI + 524288;        // cross q [l,b,128]
constexpr size_t OFF_QCI = OFF_QCR + 131072;
constexpr size_t OFF_KCR = OFF_QCI + 131072;
constexpr size_t OFF_KCI = OFF_KCR + 131072;
constexpr size_t OFF_AC  = OFF_KCI + 131072;        // cross scores -> A [b,512,512]
constexpr size_t OFF_T3R = OFF_AC + 524288;         // t3 partial kc=0 (then z)
constexpr size_t OFF_T3I = OFF_T3R + 524288;
constexpr size_t OFF_MR  = OFF_T3I + 524288;        // mask scalar [b,512]
constexpr size_t OFF_MI  = OFF_MR + 1024;
constexpr size_t OFF_P1  = OFF_MI + 1024;           // ss partials (16 groups x 32)
constexpr size_t OFF_P2  = OFF_P1 + 512;
constexpr size_t OFF_P3  = OFF_P2 + 512;

// ---- reductions ----
template<int NT>
__device__ __forceinline__ float blk_sum(float v, float* sh) {
  int tid = threadIdx.x;
  sh[tid] = v; __syncthreads();
  #pragma unroll
  for (int s = NT/2; s > 0; s >>= 1) { if (tid < s) sh[tid] += sh[tid+s]; __syncthreads(); }
  float r = sh[0]; __syncthreads(); return r;
}
template<int NT>
__device__ __forceinline__ float blk_max(float v, float* sh) {
  int tid = threadIdx.x;
  sh[tid] = v; __syncthreads();
  #pragma unroll
  for (int s = NT/2; s > 0; s >>= 1) { if (tid < s) sh[tid] = fmaxf(sh[tid], sh[tid+s]); __syncthreads(); }
  float r = sh[0]; __syncthreads(); return r;
}
__device__ __forceinline__ float wave_sum32(float v) {
  #pragma unroll
  for (int o = 16; o; o >>= 1) v += __shfl_xor(v, o, 64);
  return v;
}
// inline IN-scale from 32 partials: 4*rsqrt(ss+1e-5)
__device__ __forceinline__ float scale_from(const float* part, int q) {
  float ss = 0.f;
  #pragma unroll
  for (int j = 0; j < NBLK_; ++j) ss += part[q*NBLK_ + j];
  return 4.f * rsqrtf(ss + 1e-5f);
}

// ---- 1: tokenize transpose: [n,b,d,hw] -> [(n*hw),b,d] ----
__global__ void k_transpose(const float* sR, const float* sI, const float* tR, const float* tI, float* ws) {
  int which = blockIdx.y;
  const float* in = (which==0)? sR : (which==1)? sI : (which==2)? tR : tI;
  float* out = ws + ((which==0)? OFF_TSR : (which==1)? OFF_TSI : (which==2)? OFF_TTR : OFF_TTI);
  int bx = blockIdx.x;               // 128 = nb(4)*dt(8)*pt(4)
  int pt = bx & 3, dt = (bx>>2)&7, nb = bx>>5;
  int ni = nb>>1, bi = nb&1;
  __shared__ float tile[64][65];
  int tid = threadIdx.x;
  int p0 = pt*64, d0 = dt*64;
  #pragma unroll
  for (int it=0; it<16; ++it) {
    int i = it*256 + tid; int row = i>>6, col = i&63;
    tile[row][col] = in[(size_t)(nb*D_ + d0+row)*HW_ + p0+col];
  }
  __syncthreads();
  #pragma unroll
  for (int it=0; it<16; ++it) {
    int i = it*256 + tid; int row = i>>6, col = i&63;
    out[(size_t)((ni*HW_ + p0+row)*B_ + bi)*D_ + d0+col] = tile[col][row];
  }
}

// ---- 2: rel q projection + cnorm (8 rows/block, W amortized) ----
__global__ void __launch_bounds__(256) k_qrel(float* ws, const float* WK) {
  int bx = blockIdx.x;               // 256 = which(2)*rg(128)
  int rg = bx & 127, which = bx >> 7;
  const float* Tr = ws + (which ? OFF_TTR : OFF_TSR);
  const float* Ti = ws + (which ? OFF_TTI : OFF_TSI);
  float* Qr = ws + (which ? OFF_QTR : OFF_QSR);
  float* Qi = ws + (which ? OFF_QTI : OFF_QSI);
  int R0 = rg*8;
  __shared__ float Xr[8][512], Xi[8][512];
  int tid = threadIdx.x;
  const float4* tr4 = (const float4*)(Tr + (size_t)R0*D_);
  const float4* ti4 = (const float4*)(Ti + (size_t)R0*D_);
  #pragma unroll
  for (int it=0; it<4; ++it) {
    int i = it*256 + tid;
    ((float4*)&Xr[0][0])[i] = tr4[i];
    ((float4*)&Xi[0][0])[i] = ti4[i];
  }
  __syncthreads();
  int row = tid >> 5, col2 = (tid & 31)*2;
  float a0r=0.f, a0i=0.f, a1r=0.f, a1i=0.f;
  #pragma unroll 4
  for (int d=0; d<512; ++d) {
    float2 w = *(const float2*)&WK[(size_t)d*DK_ + col2];
    float xr = Xr[row][d], xi = Xi[row][d];
    a0r += xr*w.x; a1r += xr*w.y;
    a0i += xi*w.x; a1i += xi*w.y;
  }
  float ss = wave_sum32(a0r*a0r + a1r*a1r + a0i*a0i + a1i*a1i);
  float inv = 1.f / sqrtf(ss + 1e-12f);
  size_t o = (size_t)(R0+row)*DK_ + col2;
  Qr[o]   = a0r*inv; Qr[o+1] = a1r*inv;
  Qi[o]   = a0i*inv; Qi[o+1] = a1i*inv;
}

// ---- 2b: gram scores G = Qr Qr^T + Qi Qi^T, written into A buffers ----
__global__ void __launch_bounds__(128) k_gram(float* ws) {
  int bx = blockIdx.x;               // 256 = which(2)*nb(4)*qt(8)*lt(4)
  int lt = bx & 3, qt = (bx>>2)&7, nb = (bx>>5)&3, which = bx>>7;
  int ni = nb>>1, bi = nb&1;
  const float* Qr = ws + (which ? OFF_QTR : OFF_QSR);
  const float* Qi = ws + (which ? OFF_QTI : OFF_QSI);
  float* A = ws + (which ? OFF_AT : OFF_AS) + (size_t)nb*65536;
  __shared__ float Qrs[32][33], Qis[32][33], Krs[32][68], Kis[32][68];
  int tid = threadIdx.x, ty = tid>>4, tx = tid&15;
  int ty4 = ty*4, tx4 = tx*4;
  float acc[4][4] = {};
  for (int c = 0; c < 2; ++c) {
    #pragma unroll
    for (int it = 0; it < 8; ++it) {
      int i = it*128 + tid; int row = i>>5, col = i&31;
      size_t qa = (size_t)((ni*HW_ + qt*32+row)*B_ + bi)*DK_ + c*32 + col;
      Qrs[row][col] = Qr[qa];
      Qis[row][col] = Qi[qa];
    }
    #pragma unroll
    for (int it = 0; it < 16; ++it) {
      int i = it*128 + tid; int kk = i&31, col = i>>5;
      size_t ka = (size_t)((ni*HW_ + lt*64+col)*B_ + bi)*DK_ + c*32 + kk;
      Krs[kk][col] = Qr[ka];
      Kis[kk][col] = Qi[ka];
    }
    __syncthreads();
    #pragma unroll
    for (int kk = 0; kk < 32; ++kk) {
      float4 kr = *(const float4*)&Krs[kk][tx4];
      float4 ki = *(const float4*)&Kis[kk][tx4];
      #pragma unroll
      for (int i = 0; i < 4; ++i) {
        float qr = Qrs[ty4+i][kk], qi = Qis[ty4+i][kk];
        acc[i][0] += qr*kr.x + qi*ki.x;
        acc[i][1] += qr*kr.y + qi*ki.y;
        acc[i][2] += qr*kr.z + qi*ki.z;
        acc[i][3] += qr*kr.w + qi*ki.w;
      }
    }
    __syncthreads();
  }
  #pragma unroll
  for (int i = 0; i < 4; ++i)
    #pragma unroll
    for (int j = 0; j < 4; ++j)
      A[(size_t)(qt*32+ty4+i)*256 + lt*64+tx4+j] = acc[i][j];
}

// ---- 3: rel self-attn emb scores + softmax. TLP (2048 blocks, 8/CU) AND
// ILP (double-buffered 4-k chunks, 64 VGPR of buffers -> fits under the
// launch_bounds(256,4) 128-VGPR cap so RA cannot break the pipeline). ----
#define LOAD4(BR, BI, C)                                         \
  _Pragma("unroll")                                              \
  for (int t = 0; t < 4; ++t) {                                  \
    BR[t] = er4[(size_t)((C)*4 + t) * 16384];                    \
    BI[t] = ei4[(size_t)((C)*4 + t) * 16384];                    \
  }                                                              \
  __builtin_amdgcn_sched_barrier(0);
#define CONS4(BR, BI, K0)                                        \
  _Pragma("unroll")                                              \
  for (int t = 0; t < 4; ++t) {                                  \
    float fr = __shfl(qvr, (K0) + t);                            \
    float fi = __shfl(qvi, (K0) + t);                            \
    a0 += fr*BR[t].x + fi*BI[t].x;                               \
    a1 += fr*BR[t].y + fi*BI[t].y;                               \
    a2 += fr*BR[t].z + fi*BI[t].z;                               \
    a3 += fr*BR[t].w + fi*BI[t].w;                               \
  }                                                              \
  __builtin_amdgcn_sched_barrier(0);

__global__ void __launch_bounds__(256, 4) k_selfattn(float* ws, const float* esr, const float* esi,
                                                     const float* etr, const float* eti) {
  int idx = blockIdx.x;              // 2048 = which(2)*nb(4)*iq(256)
  int iq = idx & 255, nb = (idx>>8)&3, which = idx>>10;
  int ni = nb>>1, bi = nb&1;
  const float* Qr = ws + (which ? OFF_QTR : OFF_QSR);
  const float* Qi = ws + (which ? OFF_QTI : OFF_QSI);
  const float* er = which ? etr : esr;
  const float* ei = which ? eti : esi;
  float* Arow = ws + (which ? OFF_AT : OFF_AS) + (size_t)nb*65536 + (size_t)iq*256;
  int tid = threadIdx.x, w = tid>>6, lane = tid&63;
  int tokq = ni*HW_ + iq;
  int kl = lane & 15;                // wave w covers k = w*16 .. w*16+15
  float qvr = Qr[(size_t)(tokq*B_ + bi)*DK_ + w*16 + kl];
  float qvi = Qi[(size_t)(tokq*B_ + bi)*DK_ + w*16 + kl];
  int l0 = lane*4;
  size_t eb = (size_t)nb*4194304 + (size_t)(w*16)*65536 + (size_t)iq*256 + l0;
  const float4* er4 = (const float4*)&er[eb];
  const float4* ei4 = (const float4*)&ei[eb];
  float4 Ra[4], Ia[4], Rb[4], Ib[4];
  float a0=0.f, a1=0.f, a2=0.f, a3=0.f;
  LOAD4(Ra, Ia, 0)
  LOAD4(Rb, Ib, 1)
  CONS4(Ra, Ia, 0)
  LOAD4(Ra, Ia, 2)
  CONS4(Rb, Ib, 4)
  LOAD4(Rb, Ib, 3)
  CONS4(Ra, Ia, 8)
  CONS4(Rb, Ib, 12)
  __shared__ float part[4][256];
  __shared__ float sh[256];
  *(float4*)&part[w][l0] = make_float4(a0,a1,a2,a3);
  __syncthreads();
  float s = (part[0][tid]+part[1][tid]+part[2][tid]+part[3][tid] + Arow[tid]) * 30.f;
  float m = blk_max<256>(s, sh);
  float e = __expf(s - m);
  float sum = blk_sum<256>(e, sh);
  Arow[tid] = e / sum;
}

// ---- 4: Y = tok + A @ tok  (32x64 tiles, 128 thr, r & i together) ----
__global__ void __launch_bounds__(128) k_selfapply(float* ws) {
  int bx = blockIdx.x;               // 512 = which(2)*nb(4)*qt(8)*dt(8)
  int dt = bx & 7, qt = (bx>>3)&7, nb = (bx>>6)&3, which = bx>>8;
  int ni = nb>>1, bi = nb&1;
  const float* A  = ws + (which ? OFF_AT : OFF_AS) + (size_t)nb*65536;
  const float* Xr = ws + (which ? OFF_TTR : OFF_TSR);
  const float* Xi = ws + (which ? OFF_TTI : OFF_TSI);
  float* Yr = ws + (which ? OFF_YTR : OFF_YSR);
  float* Yi = ws + (which ? OFF_YTI : OFF_YSI);
  __shared__ float As[32][33], Xrs[32][68], Xis[32][68];
  int tid = threadIdx.x, ty = tid>>4, tx = tid&15;
  int ty4 = ty*4, tx4 = tx*4;
  float ar[4][4] = {}, ai[4][4] = {};
  for (int c = 0; c < 8; ++c) {
    #pragma unroll
    for (int it = 0; it < 8; ++it) {
      int i = it*128 + tid; int row = i>>5, col = i&31;
      As[row][col] = A[(size_t)(qt*32+row)*256 + c*32+col];
    }
    #pragma unroll
    for (int it = 0; it < 16; ++it) {
      int i = it*128 + tid; int row = i>>6, col = i&63;
      size_t xb = (size_t)((ni*HW_ + c*32+row)*B_ + bi)*D_ + dt*64+col;
      Xrs[row][col] = Xr[xb]; Xis[row][col] = Xi[xb];
    }
    __syncthreads();
    #pragma unroll
    for (int kk = 0; kk < 32; ++kk) {
      float4 vr = *(const float4*)&Xrs[kk][tx4];
      float4 vi = *(const float4*)&Xis[kk][tx4];
      #pragma unroll
      for (int i = 0; i < 4; ++i) {
        float a = As[ty4+i][kk];
        ar[i][0] += a*vr.x; ar[i][1] += a*vr.y; ar[i][2] += a*vr.z; ar[i][3] += a*vr.w;
        ai[i][0] += a*vi.x; ai[i][1] += a*vi.y; ai[i][2] += a*vi.z; ai[i][3] += a*vi.w;
      }
    }
    __syncthreads();
  }
  #pragma unroll
  for (int i = 0; i < 4; ++i) {
    size_t o = (size_t)((ni*HW_ + qt*32 + ty4+i)*B_ + bi)*D_ + dt*64 + tx4;
    #pragma unroll
    for (int j = 0; j < 4; ++j) { Yr[o+j] = Xr[o+j] + ar[i][j]; Yi[o+j] = Xi[o+j] + ai[i][j]; }
  }
}

// ---- 5: P1 = ss(Y) partials per (n,b) for the 4 UNSCALED Y arrays ----
__global__ void k_reduce4(float* ws) {
  int qy = blockIdx.y;
  const float* a = ws + ((qy==0)? OFF_YSR : (qy==1)? OFF_YSI : (qy==2)? OFF_YTR : OFF_YTI);
  int g = blockIdx.x / NBLK_, blk = blockIdx.x % NBLK_;
  int ni = g>>1, bi = g&1;
  int tid = threadIdx.x;
  float acc = 0.f;
  for (int p = blk; p < HW_; p += NBLK_) {
    const float* row = a + (size_t)((ni*HW_ + p)*B_ + bi)*D_;
    for (int d = tid; d < D_; d += 256) { float v = row[d]; acc += v*v; }
  }
  __shared__ float sh[256];
  float s = blk_sum<256>(acc, sh);
  if (!tid) ws[OFF_P1 + (size_t)(qy*G_ + g)*NBLK_ + blk] = s;
}

// ---- 8: cross q/k projection + cnorm (reads UNSCALED Y; scales applied to
// the projection outputs before the joint norm: (s*x)@W = s*(x@W)) ----
__global__ void __launch_bounds__(256) k_crossproj(float* ws, const float* W) {
  int bx = blockIdx.x;               // 256 = isK(2)*rg(128)
  int rg = bx & 127, isK = bx >> 7;
  const float* inR = ws + (isK ? OFF_YSR : OFF_YTR);
  const float* inI = ws + (isK ? OFF_YSI : OFF_YTI);
  float* oR = ws + (isK ? OFF_KCR : OFF_QCR);
  float* oI = ws + (isK ? OFF_KCI : OFF_QCI);
  int R0 = rg*8;
  __shared__ float Xr[8][512], Xi[8][512];
  int tid = threadIdx.x;
  const float4* xr4 = (const float4*)(inR + (size_t)R0*D_);
  const float4* xi4 = (const float4*)(inI + (size_t)R0*D_);
  #pragma unroll
  for (int it=0; it<4; ++it) {
    int i = it*256 + tid;
    ((float4*)&Xr[0][0])[i] = xr4[i];
    ((float4*)&Xi[0][0])[i] = xi4[i];
  }
  __syncthreads();
  int row = tid >> 5, col4 = (tid & 31)*4;
  float ar[4]={}, ai[4]={};
  #pragma unroll 4
  for (int d=0; d<512; ++d) {
    float4 w = *(const float4*)&W[(size_t)d*DKC_ + col4];
    float xr = Xr[row][d], xi = Xi[row][d];
    ar[0] += xr*w.x; ar[1] += xr*w.y; ar[2] += xr*w.z; ar[3] += xr*w.w;
    ai[0] += xi*w.x; ai[1] += xi*w.y; ai[2] += xi*w.z; ai[3] += xi*w.w;
  }
  // per-row IN scales (real and imag differ -> joint cnorm needs them)
  int rr = R0 + row;
  int bi = rr & 1, gg = ((rr>>1)>>8)*2 + bi;
  float sR = scale_from(ws + OFF_P1, (isK?0:2)*G_ + gg);
  float sI = scale_from(ws + OFF_P1, (isK?1:3)*G_ + gg);
  ar[0]*=sR; ar[1]*=sR; ar[2]*=sR; ar[3]*=sR;
  ai[0]*=sI; ai[1]*=sI; ai[2]*=sI; ai[3]*=sI;
  float ps = ar[0]*ar[0]+ar[1]*ar[1]+ar[2]*ar[2]+ar[3]*ar[3]
           + ai[0]*ai[0]+ai[1]*ai[1]+ai[2]*ai[2]+ai[3]*ai[3];
  float ss = wave_sum32(ps);
  float inv = 1.f / sqrtf(ss + 1e-12f);
  size_t o = (size_t)rr*DKC_ + col4;
  oR[o]   = ar[0]*inv; oR[o+1] = ar[1]*inv; oR[o+2] = ar[2]*inv; oR[o+3] = ar[3]*inv;
  oI[o]   = ai[0]*inv; oI[o+1] = ai[1]*inv; oI[o+2] = ai[2]*inv; oI[o+3] = ai[3]*inv;
}

// ---- 9: raw cross scores S = Qr Kr^T + Qi Ki^T  (32x64 tiles) ----
__global__ void __launch_bounds__(128) k_crossscore(float* ws) {
  int bx = blockIdx.x;               // 256 = bi(2)*qt(16)*lt(8)
  int lt = bx & 7, qt = (bx>>3)&15, bi = bx>>7;
  const float* Qr = ws + OFF_QCR; const float* Qi = ws + OFF_QCI;
  const float* Kr = ws + OFF_KCR; const float* Ki = ws + OFF_KCI;
  float* S = ws + OFF_AC + (size_t)bi*262144;
  __shared__ float Qrs[32][33], Qis[32][33], Krs[32][68], Kis[32][68];
  int tid = threadIdx.x, ty = tid>>4, tx = tid&15;
  int ty4 = ty*4, tx4 = tx*4;
  float acc[4][4] = {};
  for (int c = 0; c < 4; ++c) {
    #pragma unroll
    for (int it = 0; it < 8; ++it) {
      int i = it*128 + tid; int row = i>>5, col = i&31;
      Qrs[row][col] = Qr[(size_t)((qt*32+row)*B_ + bi)*DKC_ + c*32 + col];
      Qis[row][col] = Qi[(size_t)((qt*32+row)*B_ + bi)*DKC_ + c*32 + col];
    }
    #pragma unroll
    for (int it = 0; it < 16; ++it) {
      int i = it*128 + tid; int kk = i&31, col = i>>5;
      Krs[kk][col] = Kr[(size_t)((lt*64+col)*B_ + bi)*DKC_ + c*32 + kk];
      Kis[kk][col] = Ki[(size_t)((lt*64+col)*B_ + bi)*DKC_ + c*32 + kk];
    }
    __syncthreads();
    #pragma unroll
    for (int kk = 0; kk < 32; ++kk) {
      float4 kr = *(const float4*)&Krs[kk][tx4];
      float4 ki = *(const float4*)&Kis[kk][tx4];
      #pragma unroll
      for (int i = 0; i < 4; ++i) {
        float qr = Qrs[ty4+i][kk], qi = Qis[ty4+i][kk];
        acc[i][0] += qr*kr.x + qi*ki.x;
        acc[i][1] += qr*kr.y + qi*ki.y;
        acc[i][2] += qr*kr.z + qi*ki.z;
        acc[i][3] += qr*kr.w + qi*ki.w;
      }
    }
    __syncthreads();
  }
  #pragma unroll
  for (int i = 0; i < 4; ++i)
    #pragma unroll
    for (int j = 0; j < 4; ++j)
      S[(size_t)(qt*32+ty4+i)*512 + lt*64+tx4+j] = acc[i][j];
}

// ---- 10: softmax per row (in-place) + mask scalars m = A @ pos ----
__global__ void k_softmaxrow(float* ws, const float* posr, const float* posi) {
  int bx = blockIdx.x;               // 1024 = b*512
  int bi = bx >> 9, iq = bx & 511;
  float* row = ws + OFF_AC + (size_t)bi*262144 + (size_t)iq*512;
  int tid = threadIdx.x;             // 256
  float s0 = row[tid]*30.f, s1 = row[tid+256]*30.f;
  __shared__ float sh[256];
  float m = blk_max<256>(fmaxf(s0, s1), sh);
  float e0 = __expf(s0 - m), e1 = __expf(s1 - m);
  float sum = blk_sum<256>(e0 + e1, sh);
  float inv = 1.f / sum;
  float a0 = e0*inv, a1 = e1*inv;
  row[tid] = a0; row[tid+256] = a1;
  float pr0 = posr[bi*HW_ + tid],        pr1 = posr[(B_+bi)*HW_ + tid];
  float pi0 = posi[bi*HW_ + tid],        pi1 = posi[(B_+bi)*HW_ + tid];
  float mr = blk_sum<256>(a0*pr0 + a1*pr1, sh);
  float mi = blk_sum<256>(a0*pi0 + a1*pi1, sh);
  if (!tid) { ws[OFF_MR + bi*512 + iq] = mr; ws[OFF_MI + bi*512 + iq] = mi; }
}

// ---- 11: t3 = A @ (s_mem*mem * pos), split-K=2, partials ----
__global__ void __launch_bounds__(128) k_crossapply(float* ws, const float* posr, const float* posi) {
  int bx = blockIdx.x;               // 512 = kc(2)*bi(2)*qt(16)*dt(8)
  int dt = bx & 7, qt = (bx>>3)&15, bi = (bx>>7)&1, kc = bx>>8;
  const float* A  = ws + OFF_AC + (size_t)bi*262144;
  const float* Mr = ws + OFF_YSR; const float* Mi = ws + OFF_YSI;
  float* Pr = ws + (kc ? OFF_TSR : OFF_T3R);
  float* Pi = ws + (kc ? OFF_TSI : OFF_T3I);
  // kc selects l in [kc*256,(kc+1)*256) -> ni = kc for all rows in this block
  float smr = scale_from(ws + OFF_P1, 0*G_ + kc*2 + bi);
  float smi = scale_from(ws + OFF_P1, 1*G_ + kc*2 + bi);
  __shared__ float As[32][33], Vrs[32][68], Vis[32][68];
  int tid = threadIdx.x, ty = tid>>4, tx = tid&15;
  int ty4 = ty*4, tx4 = tx*4;
  float ar[4][4] = {}, ai[4][4] = {};
  for (int c = 0; c < 8; ++c) {
    int kb = kc*256 + c*32;
    #pragma unroll
    for (int it = 0; it < 8; ++it) {
      int i = it*128 + tid; int row = i>>5, col = i&31;
      As[row][col] = A[(size_t)(qt*32+row)*512 + kb+col];
    }
    #pragma unroll
    for (int it = 0; it < 16; ++it) {
      int i = it*128 + tid; int row = i>>6, col = i&63;
      int l = kb + row; int pl = l & 255;
      float pvr = posr[(kc*B_ + bi)*HW_ + pl] * smr;
      float pvi = posi[(kc*B_ + bi)*HW_ + pl] * smi;
      size_t vb = (size_t)(l*B_ + bi)*D_ + dt*64+col;
      Vrs[row][col] = Mr[vb] * pvr;
      Vis[row][col] = Mi[vb] * pvi;
    }
    __syncthreads();
    #pragma unroll
    for (int kk = 0; kk < 32; ++kk) {
      float4 vr = *(const float4*)&Vrs[kk][tx4];
      float4 vi = *(const float4*)&Vis[kk][tx4];
      #pragma unroll
      for (int i = 0; i < 4; ++i) {
        float a = As[ty4+i][kk];
        ar[i][0] += a*vr.x; ar[i][1] += a*vr.y; ar[i][2] += a*vr.z; ar[i][3] += a*vr.w;
        ai[i][0] += a*vi.x; ai[i][1] += a*vi.y; ai[i][2] += a*vi.z; ai[i][3] += a*vi.w;
      }
    }
    __syncthreads();
  }
  #pragma unroll
  for (int i = 0; i < 4; ++i) {
    size_t o = (size_t)((qt*32+ty4+i)*B_ + bi)*D_ + dt*64 + tx4;
    #pragma unroll
    for (int j = 0; j < 4; ++j) { Pr[o+j] = ar[i][j]; Pi[o+j] = ai[i][j]; }
  }
}

// ---- 12: P2 = ss((sx*x)*m) (qy 0,1) and ss(sx*x + t3) (qy 2,3) ----
__global__ void k_reducey24(float* ws) {
  int qy = blockIdx.y;
  int g = blockIdx.x / NBLK_, blk = blockIdx.x % NBLK_;
  int ni = g>>1, bi = g&1;
  const float* X   = ws + ((qy==0 || qy==2) ? OFF_YTR : OFF_YTI);
  const float* T3a = ws + ((qy==2) ? OFF_T3R : OFF_T3I);
  const float* T3b = ws + ((qy==2) ? OFF_TSR : OFF_TSI);
  const float* M   = ws + ((qy==0) ? OFF_MR : OFF_MI);
  float sx = scale_from(ws + OFF_P1, ((qy==0||qy==2) ? 2 : 3)*G_ + g);
  int tid = threadIdx.x;
  float acc = 0.f;
  for (int p = blk; p < HW_; p += NBLK_) {
    int l = ni*HW_ + p;
    size_t rb = (size_t)(l*B_ + bi)*D_;
    if (qy < 2) {
      float m = M[bi*512 + l] * sx;
      for (int d = tid; d < D_; d += 256) { float v = X[rb+d]*m; acc += v*v; }
    } else {
      for (int d = tid; d < D_; d += 256) { float v = X[rb+d]*sx + T3a[rb+d] + T3b[rb+d]; acc += v*v; }
    }
  }
  __shared__ float sh[256];
  float s = blk_sum<256>(acc, sh);
  if (!tid) ws[OFF_P2 + (size_t)(qy*G_ + g)*NBLK_ + blk] = s;
}

// ---- 14: z = a2*(sx*x*m) + a4*(sx*x + t3) (into T3a) + P3 = ss(z) ----
__global__ void k_combine(float* ws) {
  int y = blockIdx.y;                // 0=r, 1=i
  int g = blockIdx.x / NBLK_, blk = blockIdx.x % NBLK_;
  int ni = g>>1, bi = g&1;
  const float* X   = ws + (y ? OFF_YTI : OFF_YTR);
  float* T3a       = ws + (y ? OFF_T3I : OFF_T3R);
  const float* T3b = ws + (y ? OFF_TSI : OFF_TSR);
  const float* M   = ws + (y ? OFF_MI : OFF_MR);
  float sx = scale_from(ws + OFF_P1, (2+y)*G_ + g);
  float a2 = scale_from(ws + OFF_P2, y*G_ + g);
  float a4 = scale_from(ws + OFF_P2, (2+y)*G_ + g);
  int tid = threadIdx.x;
  float acc = 0.f;
  for (int p = blk; p < HW_; p += NBLK_) {
    int l = ni*HW_ + p;
    float m = M[bi*512 + l];
    size_t rb = (size_t)(l*B_ + bi)*D_;
    for (int d = tid; d < D_; d += 256) {
      float x = X[rb+d] * sx;
      float z = a2*(x*m) + a4*(x + T3a[rb+d] + T3b[rb+d]);
      T3a[rb+d] = z;
      acc += z*z;
    }
  }
  __shared__ float sh[256];
  float s = blk_sum<256>(acc, sh);
  if (!tid) ws[OFF_P3 + (size_t)(y*G_ + g)*NBLK_ + blk] = s;
}

// ---- 16: out = z*scale; feat = transpose(out) ----
__global__ void k_final(float* ws, float* out) {
  int y = blockIdx.y;                // 0=r, 1=i
  int bx = blockIdx.x;               // 128 = nb(4)*dt(8)*pt(4)
  int pt = bx & 3, dt = (bx>>2)&7, nb = bx>>5;
  int ni = nb>>1, bi = nb&1;
  const float* Z = ws + (y ? OFF_T3I : OFF_T3R);
  float s = scale_from(ws + OFF_P3, y*G_ + nb);
  float* o1 = out + (size_t)y*524288;        // out_r / out_i
  float* o2 = out + (size_t)(2+y)*524288;    // feat_r / feat_i
  __shared__ float tile[64][65];
  int tid = threadIdx.x;
  int p0 = pt*64, d0 = dt*64;
  #pragma unroll
  for (int it = 0; it < 16; ++it) {
    int i = it*256 + tid; int row = i>>6, col = i&63;
    size_t idx = (size_t)((ni*HW_ + p0+row)*B_ + bi)*D_ + d0+col;
    float v = Z[idx] * s;
    o1[idx] = v;
    tile[row][col] = v;
  }
  __syncthreads();
  #pragma unroll
  for (int it = 0; it < 16; ++it) {
    int i = it*256 + tid; int row = i>>6, col = i&63;
    o2[(size_t)(nb*D_ + d0+row)*HW_ + p0+col] = tile[col][row];
  }
}

extern "C" void kernel_launch(void* const* d_in, const int* in_sizes, int n_in,
                              void* d_out, int out_size, void* d_ws, size_t ws_size,
                              hipStream_t stream) {
  const float* srcR = (const float*)d_in[0];
  const float* srcI = (const float*)d_in[1];
  const float* tgtR = (const float*)d_in[2];
  const float* tgtI = (const float*)d_in[3];
  const float* esr  = (const float*)d_in[4];
  const float* esi  = (const float*)d_in[5];
  const float* etr  = (const float*)d_in[6];
  const float* eti  = (const float*)d_in[7];
  const float* posR = (const float*)d_in[8];
  const float* posI = (const float*)d_in[9];
  const float* WKrel   = (const float*)d_in[10];
  const float* WKcross = (const float*)d_in[11];
  float* ws  = (float*)d_ws;
  float* out = (float*)d_out;

  k_transpose <<<dim3(128,4), 256, 0, stream>>>(srcR, srcI, tgtR, tgtI, ws);
  k_qrel      <<<256, 256, 0, stream>>>(ws, WKrel);
  k_gram      <<<256, 128, 0, stream>>>(ws);
  k_selfattn  <<<2048, 256, 0, stream>>>(ws, esr, esi, etr, eti);
  k_selfapply <<<512, 128, 0, stream>>>(ws);
  k_reduce4   <<<dim3(G_*NBLK_,4), 256, 0, stream>>>(ws);
  k_crossproj <<<256, 256, 0, stream>>>(ws, WKcross);
  k_crossscore<<<256, 128, 0, stream>>>(ws);
  k_softmaxrow<<<1024, 256, 0, stream>>>(ws, posR, posI);
  k_crossapply<<<512, 128, 0, stream>>>(ws, posR, posI);
  k_reducey24 <<<dim3(G_*NBLK_,4), 256, 0, stream>>>(ws);
  k_combine   <<<dim3(G_*NBLK_,2), 256, 0, stream>>>(ws);
  k_final     <<<dim3(128,2), 256, 0, stream>>>(ws, out);
}